// Round 7
// baseline (156.697 us; speedup 1.0000x reference)
//
#include <hip/hip_runtime.h>
#include <hip/hip_bf16.h>

typedef __attribute__((ext_vector_type(4))) float f32x4;
typedef __attribute__((ext_vector_type(8))) short bf16x8;

#define NROWS 32768
#define DIM   2048
#define NEXP  64
#define BKF   128              // K-chunk (f32 elements)
#define NCH   (DIM / BKF)      // 16 chunks

__device__ __forceinline__ short f2bf(float f) {
    __hip_bfloat16 h = __float2bfloat16(f);   // RTNE
    short s;
    __builtin_memcpy(&s, &h, 2);
    return s;
}

// async global->LDS DMA, 16B per lane; LDS dest wave-uniform (HW adds lane*16).
__device__ __forceinline__ void async16(const void* g, void* l) {
    __builtin_amdgcn_global_load_lds(
        (const __attribute__((address_space(1))) unsigned int*)g,
        (__attribute__((address_space(3))) unsigned int*)l, 16, 0, 0);
}

// ---------------- Kernel A: expert prep -------------------------------------
__global__ __launch_bounds__(256) void prep_experts(
    const float* __restrict__ ek,
    short* __restrict__ ekbf,
    short* __restrict__ ekT,
    float* __restrict__ enorm)
{
    const int e = blockIdx.x;
    const int t = threadIdx.x;
    const float* row = ek + e * DIM;
    float ss = 0.f;
#pragma unroll
    for (int i = 0; i < 2; ++i) {
        const int c4 = t + i * 256;
        const float4 v = ((const float4*)row)[c4];
        ss += v.x * v.x + v.y * v.y + v.z * v.z + v.w * v.w;
        short4 b;
        b.x = f2bf(v.x); b.y = f2bf(v.y); b.z = f2bf(v.z); b.w = f2bf(v.w);
        *(short4*)(ekbf + e * DIM + c4 * 4) = b;
        const int d = c4 * 4;
        ekT[(d + 0) * NEXP + e] = b.x;
        ekT[(d + 1) * NEXP + e] = b.y;
        ekT[(d + 2) * NEXP + e] = b.z;
        ekT[(d + 3) * NEXP + e] = b.w;
    }
#pragma unroll
    for (int s = 1; s < 64; s <<= 1) ss += __shfl_xor(ss, s);
    __shared__ float red[4];
    if ((t & 63) == 0) red[t >> 6] = ss;
    __syncthreads();
    if (t == 0) enorm[e] = sqrtf(red[0] + red[1] + red[2] + red[3]);
}

// ---------------- Kernel 1: similarity (read-bound) -------------------------
// 32 rows/block, 1024 blocks, 4 waves. Streaming DMA staging as R6, but:
// z 3-deep (2-chunk lookahead, HBM), ek 2-deep (1-chunk lookahead, L2),
// FIFO-ordered issue -> entry wait is exactly vmcnt(4); ONE barrier/chunk.
__global__ __launch_bounds__(256) void sim_kernel(
    const float* __restrict__ z,
    const short* __restrict__ ekbf,   // [64][2048] bf16
    const float* __restrict__ enorm,  // [64]
    float* __restrict__ out_sim)      // [32768][64]
{
    const int tid = threadIdx.x;
    const int w   = tid >> 6;
    const int l   = tid & 63;
    const int lr  = l & 15;
    const int lg  = l >> 4;
    const int base = blockIdx.x * 32;

    __shared__ __align__(16) float zbuf[3][32][BKF];   // 48 KiB
    __shared__ __align__(16) short ebuf[2][64][BKF];   // 32 KiB

    f32x4 acc[2];
    acc[0] = f32x4{0.f, 0.f, 0.f, 0.f};
    acc[1] = f32x4{0.f, 0.f, 0.f, 0.f};
    float sqa[2] = {0.f, 0.f}, sqb[2] = {0.f, 0.f};

    auto STAGE_Z = [&](int c_, int slot) {
#pragma unroll
        for (int i = 0; i < 4; ++i) {               // z rows w*8 .. w*8+7
            const int r0 = w * 8 + i * 2;
            const int zr = r0 + (l >> 5);           // 2 rows/instr, 512B each
            async16(z + (size_t)(base + zr) * DIM + c_ * BKF
                      + (((l & 31) ^ (zr & 7)) << 2),
                    &zbuf[slot][r0][0]);
        }
    };
    auto STAGE_E = [&](int c_) {
        const int b_ = c_ & 1;
#pragma unroll
        for (int i = 0; i < 4; ++i) {               // ek rows w*16 .. w*16+15
            const int r0 = w * 16 + i * 4;
            const int er = r0 + (l >> 4);           // 4 rows/instr, 256B each
            async16(ekbf + (size_t)er * DIM + c_ * BKF
                         + (((l & 15) ^ (er & 7)) << 3),
                    &ebuf[b_][r0][0]);
        }
    };

    // prologue, FIFO order: z0, e0, z1  (newer-than-e0 = z1:4)
    STAGE_Z(0, 0);
    STAGE_E(0);
    STAGE_Z(1, 1);

    int zcur = 0;                                    // = c % 3
    for (int c = 0; c < NCH; ++c) {
        // steady entry FIFO: z(c):4, e(c):4, z(c+1):4 -> need z(c),e(c) done
        if (c < NCH - 1) asm volatile("s_waitcnt vmcnt(4)" ::: "memory");
        else             asm volatile("s_waitcnt vmcnt(0)" ::: "memory");
        __builtin_amdgcn_s_barrier();
        __builtin_amdgcn_sched_barrier(0);
        // issue next stages (e before z keeps the FIFO invariant)
        if (c + 1 < NCH) STAGE_E(c + 1);
        if (c + 2 < NCH) STAGE_Z(c + 2, zcur == 0 ? 2 : zcur - 1);

        const int eb = c & 1;
#pragma unroll
        for (int kk = 0; kk < BKF / 32; ++kk) {
            const int eu = ((kk * 4 + lg) ^ (lr & 7)) << 4;
            const bf16x8 bf =
                *(const bf16x8*)((const char*)&ebuf[eb][w * 16 + lr][0] + eu);
#pragma unroll
            for (int mt = 0; mt < 2; ++mt) {
                const int zr = mt * 16 + lr;
                const int u0 = ((kk * 8 + lg * 2)     ^ (lr & 7)) << 4;
                const int u1 = ((kk * 8 + lg * 2 + 1) ^ (lr & 7)) << 4;
                const float4 a0 = *(const float4*)((const char*)&zbuf[zcur][zr][0] + u0);
                const float4 a1 = *(const float4*)((const char*)&zbuf[zcur][zr][0] + u1);
                sqa[mt] = fmaf(a0.x, a0.x, sqa[mt]); sqb[mt] = fmaf(a0.y, a0.y, sqb[mt]);
                sqa[mt] = fmaf(a0.z, a0.z, sqa[mt]); sqb[mt] = fmaf(a0.w, a0.w, sqb[mt]);
                sqa[mt] = fmaf(a1.x, a1.x, sqa[mt]); sqb[mt] = fmaf(a1.y, a1.y, sqb[mt]);
                sqa[mt] = fmaf(a1.z, a1.z, sqa[mt]); sqb[mt] = fmaf(a1.w, a1.w, sqb[mt]);
                bf16x8 af;
                af[0] = f2bf(a0.x); af[1] = f2bf(a0.y); af[2] = f2bf(a0.z); af[3] = f2bf(a0.w);
                af[4] = f2bf(a1.x); af[5] = f2bf(a1.y); af[6] = f2bf(a1.z); af[7] = f2bf(a1.w);
                acc[mt] = __builtin_amdgcn_mfma_f32_16x16x32_bf16(af, bf, acc[mt], 0, 0, 0);
            }
        }
        zcur = (zcur == 2) ? 0 : zcur + 1;
    }

    // norms + similarity write. C layout: lane holds D[lg*4+j][lr].
    const float en = enorm[w * 16 + lr];
#pragma unroll
    for (int mt = 0; mt < 2; ++mt) {
        float ss = sqa[mt] + sqb[mt];
        ss += __shfl_xor(ss, 16);
        ss += __shfl_xor(ss, 32);
        const float zn = sqrtf(ss);                  // ||z[base+mt*16+lr]||
#pragma unroll
        for (int j = 0; j < 4; ++j) {
            const float znj = __shfl(zn, lg * 4 + j);
            out_sim[(size_t)(base + mt * 16 + lg * 4 + j) * NEXP + w * 16 + lr]
                = acc[mt][j] / fmaxf(znj * en, 1e-8f);
        }
    }
}

// ---------------- Kernel 2: softmax + weighted combine (write-bound) --------
__global__ __launch_bounds__(256) void moe_kernel(
    const float* __restrict__ sim,    // [32768][64]
    const short* __restrict__ ekT,    // [2048][64] bf16
    float* __restrict__ out_wei)      // [32768][2048]
{
    const int tid = threadIdx.x;
    const int w   = tid >> 6;
    const int l   = tid & 63;
    const int lr  = l & 15;
    const int lg  = l >> 4;
    const int base = blockIdx.x * 32;
    const int col0 = blockIdx.y * 1024 + w * 256;

    __shared__ __align__(16) short WL[32][64];      // [row][e], 16B-unit XOR swizzled
    __shared__ __align__(16) float tbuf[4][32][68]; // per-wave transpose buffer

    {   // softmax: thread t -> row t>>3, experts (t&7)*8..+8
        const int r  = tid >> 3;
        const int cc = tid & 7;
        const float* sp = sim + (size_t)(base + r) * NEXP + cc * 8;
        const float4 v0 = *(const float4*)sp;
        const float4 v1 = *(const float4*)(sp + 4);
        float va[8] = {v0.x, v0.y, v0.z, v0.w, v1.x, v1.y, v1.z, v1.w};
        float m = va[0];
#pragma unroll
        for (int i = 1; i < 8; ++i) m = fmaxf(m, va[i]);
        m = fmaxf(m, __shfl_xor(m, 1));
        m = fmaxf(m, __shfl_xor(m, 2));
        m = fmaxf(m, __shfl_xor(m, 4));
        float sum = 0.f;
#pragma unroll
        for (int i = 0; i < 8; ++i) { va[i] = __expf(va[i] - m); sum += va[i]; }
        sum += __shfl_xor(sum, 1);
        sum += __shfl_xor(sum, 2);
        sum += __shfl_xor(sum, 4);
        const float inv = 1.0f / sum;
        bf16x8 wv;
#pragma unroll
        for (int i = 0; i < 8; ++i) wv[i] = f2bf(va[i] * inv);
        *(bf16x8*)&WL[r][(cc ^ (r & 7)) * 8] = wv;
    }
    __syncthreads();

    bf16x8 afr[2][2];
#pragma unroll
    for (int mt = 0; mt < 2; ++mt)
#pragma unroll
        for (int ks = 0; ks < 2; ++ks) {
            const int row = mt * 16 + lr;
            const int u   = (ks * 4 + lg) ^ (row & 7);
            afr[mt][ks] = *(const bf16x8*)&WL[row][u * 8];
        }

#pragma unroll 1
    for (int g = 0; g < 4; ++g) {
        f32x4 oacc[4][2];
#pragma unroll
        for (int nt2 = 0; nt2 < 4; ++nt2) {
            const int d0 = col0 + g * 64 + nt2 * 16;
            const short* bp = ekT + (size_t)(d0 + lr) * NEXP + lg * 8;
            const bf16x8 b0 = *(const bf16x8*)bp;
            const bf16x8 b1 = *(const bf16x8*)(bp + 32);
#pragma unroll
            for (int mt = 0; mt < 2; ++mt) {
                f32x4 o = f32x4{0.f, 0.f, 0.f, 0.f};
                o = __builtin_amdgcn_mfma_f32_16x16x32_bf16(afr[mt][0], b0, o, 0, 0, 0);
                o = __builtin_amdgcn_mfma_f32_16x16x32_bf16(afr[mt][1], b1, o, 0, 0, 0);
                oacc[nt2][mt] = o;
            }
        }
#pragma unroll
        for (int nt2 = 0; nt2 < 4; ++nt2)
#pragma unroll
            for (int mt = 0; mt < 2; ++mt)
#pragma unroll
                for (int j = 0; j < 4; ++j)
                    tbuf[w][mt * 16 + lg * 4 + j][nt2 * 16 + lr] = oacc[nt2][mt][j];
#pragma unroll
        for (int i = 0; i < 8; ++i) {
            const int row  = (l >> 4) + i * 4;
            const int unit = l & 15;
            const float4 t = *(const float4*)&tbuf[w][row][unit * 4];
            *(float4*)&out_wei[(size_t)(base + row) * DIM + col0 + g * 64 + unit * 4] = t;
        }
    }
}

// ---------------- launch -----------------------------------------------------
extern "C" void kernel_launch(void* const* d_in, const int* in_sizes, int n_in,
                              void* d_out, int out_size, void* d_ws, size_t ws_size,
                              hipStream_t stream) {
    const float* z  = (const float*)d_in[0];
    const float* ek = (const float*)d_in[1];
    float* out_sim = (float*)d_out;
    float* out_wei = out_sim + (size_t)NROWS * NEXP;

    short* ekbf  = (short*)d_ws;                 // 256 KiB
    short* ekT   = ekbf + NEXP * DIM;            // 256 KiB
    float* enorm = (float*)(ekT + DIM * NEXP);   // 256 B

    prep_experts<<<NEXP, 256, 0, stream>>>(ek, ekbf, ekT, enorm);
    sim_kernel<<<NROWS / 32, 256, 0, stream>>>(z, ekbf, enorm, out_sim);
    moe_kernel<<<dim3(NROWS / 32, 2), 256, 0, stream>>>(out_sim, ekT, out_wei);
}

// Round 8
// 150.584 us; speedup vs baseline: 1.0406x; 1.0406x over previous
//
#include <hip/hip_runtime.h>
#include <hip/hip_bf16.h>

typedef __attribute__((ext_vector_type(4))) float f32x4;
typedef __attribute__((ext_vector_type(8))) short bf16x8;

#define NROWS 32768
#define DIM   2048
#define NEXP  64
#define BKF   128              // K-chunk (f32 elements)
#define NCH   (DIM / BKF)      // 16 chunks

__device__ __forceinline__ short f2bf(float f) {
    __hip_bfloat16 h = __float2bfloat16(f);   // RTNE
    short s;
    __builtin_memcpy(&s, &h, 2);
    return s;
}

// async global->LDS DMA, 16B per lane; LDS dest wave-uniform (HW adds lane*16).
__device__ __forceinline__ void async16(const void* g, void* l) {
    __builtin_amdgcn_global_load_lds(
        (const __attribute__((address_space(1))) unsigned int*)g,
        (__attribute__((address_space(3))) unsigned int*)l, 16, 0, 0);
}

// ---------------- Kernel A: expert prep -------------------------------------
__global__ __launch_bounds__(256) void prep_experts(
    const float* __restrict__ ek,
    short* __restrict__ ekbf,
    short* __restrict__ ekT,
    float* __restrict__ enorm)
{
    const int e = blockIdx.x;
    const int t = threadIdx.x;
    const float* row = ek + e * DIM;
    float ss = 0.f;
#pragma unroll
    for (int i = 0; i < 2; ++i) {
        const int c4 = t + i * 256;
        const float4 v = ((const float4*)row)[c4];
        ss += v.x * v.x + v.y * v.y + v.z * v.z + v.w * v.w;
        short4 b;
        b.x = f2bf(v.x); b.y = f2bf(v.y); b.z = f2bf(v.z); b.w = f2bf(v.w);
        *(short4*)(ekbf + e * DIM + c4 * 4) = b;
        const int d = c4 * 4;
        ekT[(d + 0) * NEXP + e] = b.x;
        ekT[(d + 1) * NEXP + e] = b.y;
        ekT[(d + 2) * NEXP + e] = b.z;
        ekT[(d + 3) * NEXP + e] = b.w;
    }
#pragma unroll
    for (int s = 1; s < 64; s <<= 1) ss += __shfl_xor(ss, s);
    __shared__ float red[4];
    if ((t & 63) == 0) red[t >> 6] = ss;
    __syncthreads();
    if (t == 0) enorm[e] = sqrtf(red[0] + red[1] + red[2] + red[3]);
}

// ---------------- Kernel 1: similarity (read-bound) — R6 structure ----------
// 32 rows/block, 1024 blocks, 4 waves. z and ek staged to LDS by
// global_load_lds in contiguous 1KiB spans, double-buffered, vmcnt(8),
// two barriers per chunk. Global source XOR-pre-swizzled for LDS reads.
__global__ __launch_bounds__(256) void sim_kernel(
    const float* __restrict__ z,
    const short* __restrict__ ekbf,   // [64][2048] bf16
    const float* __restrict__ enorm,  // [64]
    float* __restrict__ out_sim)      // [32768][64]
{
    const int tid = threadIdx.x;
    const int w   = tid >> 6;
    const int l   = tid & 63;
    const int lr  = l & 15;
    const int lg  = l >> 4;
    const int base = blockIdx.x * 32;

    __shared__ __align__(16) float zbuf[2][32][BKF];   // 2 x 16 KiB
    __shared__ __align__(16) short ebuf[2][64][BKF];   // 2 x 16 KiB

    f32x4 acc[2];
    acc[0] = f32x4{0.f, 0.f, 0.f, 0.f};
    acc[1] = f32x4{0.f, 0.f, 0.f, 0.f};
    float sqa[2] = {0.f, 0.f}, sqb[2] = {0.f, 0.f};

    auto STAGE = [&](int c_) {
        const int b_ = c_ & 1;
#pragma unroll
        for (int i = 0; i < 4; ++i) {               // z rows w*8 .. w*8+7
            const int r0 = w * 8 + i * 2;
            const int zr = r0 + (l >> 5);           // 2 rows/instr (512B each)
            async16(z + (size_t)(base + zr) * DIM + c_ * BKF
                      + (((l & 31) ^ (zr & 7)) << 2),
                    &zbuf[b_][r0][0]);
        }
#pragma unroll
        for (int i = 0; i < 4; ++i) {               // ek rows w*16 .. w*16+15
            const int r0 = w * 16 + i * 4;
            const int er = r0 + (l >> 4);           // 4 rows/instr (256B each)
            async16(ekbf + (size_t)er * DIM + c_ * BKF
                         + (((l & 15) ^ (er & 7)) << 3),
                    &ebuf[b_][r0][0]);
        }
    };

    STAGE(0); STAGE(1);                              // 16 DMAs/wave in flight

    for (int c = 0; c < NCH; ++c) {
        if (c < NCH - 1) asm volatile("s_waitcnt vmcnt(8)" ::: "memory");
        else             asm volatile("s_waitcnt vmcnt(0)" ::: "memory");
        __builtin_amdgcn_s_barrier();
        __builtin_amdgcn_sched_barrier(0);
        const int b = c & 1;

#pragma unroll
        for (int kk = 0; kk < BKF / 32; ++kk) {
            const int eu = ((kk * 4 + lg) ^ (lr & 7)) << 4;
            const bf16x8 bf =
                *(const bf16x8*)((const char*)&ebuf[b][w * 16 + lr][0] + eu);
#pragma unroll
            for (int mt = 0; mt < 2; ++mt) {
                const int zr = mt * 16 + lr;
                const int u0 = ((kk * 8 + lg * 2)     ^ (lr & 7)) << 4;
                const int u1 = ((kk * 8 + lg * 2 + 1) ^ (lr & 7)) << 4;
                const float4 a0 = *(const float4*)((const char*)&zbuf[b][zr][0] + u0);
                const float4 a1 = *(const float4*)((const char*)&zbuf[b][zr][0] + u1);
                sqa[mt] = fmaf(a0.x, a0.x, sqa[mt]); sqb[mt] = fmaf(a0.y, a0.y, sqb[mt]);
                sqa[mt] = fmaf(a0.z, a0.z, sqa[mt]); sqb[mt] = fmaf(a0.w, a0.w, sqb[mt]);
                sqa[mt] = fmaf(a1.x, a1.x, sqa[mt]); sqb[mt] = fmaf(a1.y, a1.y, sqb[mt]);
                sqa[mt] = fmaf(a1.z, a1.z, sqa[mt]); sqb[mt] = fmaf(a1.w, a1.w, sqb[mt]);
                bf16x8 af;
                af[0] = f2bf(a0.x); af[1] = f2bf(a0.y); af[2] = f2bf(a0.z); af[3] = f2bf(a0.w);
                af[4] = f2bf(a1.x); af[5] = f2bf(a1.y); af[6] = f2bf(a1.z); af[7] = f2bf(a1.w);
                acc[mt] = __builtin_amdgcn_mfma_f32_16x16x32_bf16(af, bf, acc[mt], 0, 0, 0);
            }
        }
        __builtin_amdgcn_s_barrier();                // all waves done reading buf
        if (c + 2 < NCH) STAGE(c + 2);
    }

    // norms + similarity write. C layout: lane holds D[lg*4+j][lr].
    const float en = enorm[w * 16 + lr];
#pragma unroll
    for (int mt = 0; mt < 2; ++mt) {
        float ss = sqa[mt] + sqb[mt];
        ss += __shfl_xor(ss, 16);
        ss += __shfl_xor(ss, 32);
        const float zn = sqrtf(ss);                  // ||z[base+mt*16+lr]||
#pragma unroll
        for (int j = 0; j < 4; ++j) {
            const float znj = __shfl(zn, lg * 4 + j);
            out_sim[(size_t)(base + mt * 16 + lg * 4 + j) * NEXP + w * 16 + lr]
                = acc[mt][j] / fmaxf(znj * en, 1e-8f);
        }
    }
}

// ---------------- Kernel 2: softmax + weighted combine (write-bound) --------
// 32 rows x 1024 cols per block, grid (1024, 2). NEW write path: wave col
// slices interleaved (wave w owns cols g*256 + w*64), fragments transposed
// into block-shared tbuf_all, then every store instruction writes a FULL
// 1 KiB contiguous row-segment (64 lanes x float4).
__global__ __launch_bounds__(256) void moe_kernel(
    const float* __restrict__ sim,    // [32768][64]
    const short* __restrict__ ekT,    // [2048][64] bf16
    float* __restrict__ out_wei)      // [32768][2048]
{
    const int tid = threadIdx.x;
    const int w   = tid >> 6;
    const int l   = tid & 63;
    const int lr  = l & 15;
    const int lg  = l >> 4;
    const int base = blockIdx.x * 32;
    const int col0 = blockIdx.y * 1024;

    __shared__ __align__(16) short WL[32][64];        // [row][e], 16B-unit XOR swizzled
    __shared__ __align__(16) float tbuf[32][260];     // block-shared 32x256 tile (+pad)

    {   // softmax: thread t -> row t>>3, experts (t&7)*8..+8
        const int r  = tid >> 3;
        const int cc = tid & 7;
        const float* sp = sim + (size_t)(base + r) * NEXP + cc * 8;
        const float4 v0 = *(const float4*)sp;
        const float4 v1 = *(const float4*)(sp + 4);
        float va[8] = {v0.x, v0.y, v0.z, v0.w, v1.x, v1.y, v1.z, v1.w};
        float m = va[0];
#pragma unroll
        for (int i = 1; i < 8; ++i) m = fmaxf(m, va[i]);
        m = fmaxf(m, __shfl_xor(m, 1));
        m = fmaxf(m, __shfl_xor(m, 2));
        m = fmaxf(m, __shfl_xor(m, 4));
        float sum = 0.f;
#pragma unroll
        for (int i = 0; i < 8; ++i) { va[i] = __expf(va[i] - m); sum += va[i]; }
        sum += __shfl_xor(sum, 1);
        sum += __shfl_xor(sum, 2);
        sum += __shfl_xor(sum, 4);
        const float inv = 1.0f / sum;
        bf16x8 wv;
#pragma unroll
        for (int i = 0; i < 8; ++i) wv[i] = f2bf(va[i] * inv);
        *(bf16x8*)&WL[r][(cc ^ (r & 7)) * 8] = wv;
    }
    __syncthreads();

    bf16x8 afr[2][2];
#pragma unroll
    for (int mt = 0; mt < 2; ++mt)
#pragma unroll
        for (int ks = 0; ks < 2; ++ks) {
            const int row = mt * 16 + lr;
            const int u   = (ks * 4 + lg) ^ (row & 7);
            afr[mt][ks] = *(const bf16x8*)&WL[row][u * 8];
        }

#pragma unroll 1
    for (int g = 0; g < 4; ++g) {
        // wave w computes cols col0 + g*256 + w*64 .. +64, rows 0..31
        f32x4 oacc[4][2];   // [nt2][mt]
#pragma unroll
        for (int nt2 = 0; nt2 < 4; ++nt2) {
            const int d0 = col0 + g * 256 + w * 64 + nt2 * 16;
            const short* bp = ekT + (size_t)(d0 + lr) * NEXP + lg * 8;
            const bf16x8 b0 = *(const bf16x8*)bp;
            const bf16x8 b1 = *(const bf16x8*)(bp + 32);
#pragma unroll
            for (int mt = 0; mt < 2; ++mt) {
                f32x4 o = f32x4{0.f, 0.f, 0.f, 0.f};
                o = __builtin_amdgcn_mfma_f32_16x16x32_bf16(afr[mt][0], b0, o, 0, 0, 0);
                o = __builtin_amdgcn_mfma_f32_16x16x32_bf16(afr[mt][1], b1, o, 0, 0, 0);
                oacc[nt2][mt] = o;
            }
        }
        // transpose fragments -> block tile [32 rows][256 cols]
#pragma unroll
        for (int nt2 = 0; nt2 < 4; ++nt2)
#pragma unroll
            for (int mt = 0; mt < 2; ++mt)
#pragma unroll
                for (int j = 0; j < 4; ++j)
                    tbuf[mt * 16 + lg * 4 + j][w * 64 + nt2 * 16 + lr] = oacc[nt2][mt][j];
        __syncthreads();
        // linear write: each wave writes 8 rows; one instruction = 1 KiB
        // contiguous (64 lanes x float4) of a single row.
#pragma unroll
        for (int i = 0; i < 8; ++i) {
            const int row = w * 8 + i;
            const float4 t = *(const float4*)&tbuf[row][l * 4];
            *(float4*)&out_wei[(size_t)(base + row) * DIM + col0 + g * 256 + l * 4] = t;
        }
        __syncthreads();   // before tbuf reuse
    }
}

// ---------------- launch -----------------------------------------------------
extern "C" void kernel_launch(void* const* d_in, const int* in_sizes, int n_in,
                              void* d_out, int out_size, void* d_ws, size_t ws_size,
                              hipStream_t stream) {
    const float* z  = (const float*)d_in[0];
    const float* ek = (const float*)d_in[1];
    float* out_sim = (float*)d_out;
    float* out_wei = out_sim + (size_t)NROWS * NEXP;

    short* ekbf  = (short*)d_ws;                 // 256 KiB
    short* ekT   = ekbf + NEXP * DIM;            // 256 KiB
    float* enorm = (float*)(ekT + DIM * NEXP);   // 256 B

    prep_experts<<<NEXP, 256, 0, stream>>>(ek, ekbf, ekT, enorm);
    sim_kernel<<<NROWS / 32, 256, 0, stream>>>(z, ekbf, enorm, out_sim);
    moe_kernel<<<dim3(NROWS / 32, 2), 256, 0, stream>>>(out_sim, ekT, out_wei);
}